// Round 17
// baseline (442.640 us; speedup 1.0000x reference)
//
#include <hip/hip_runtime.h>
#include <hip/hip_bf16.h>

#pragma clang fp contract(off)

#define BB 8
#define DD 512
#define LL 4096
#define HH 256
#define NN 2048
#define FEPS 1.1920928955078125e-07f
#define HST 260   // hsm row stride (words): 260%32=4 -> 2-way bank aliasing (free)

#define IND_OFF ((size_t)BB * DD * LL)            // 16777216
#define LOSS_OFF (IND_OFF + (size_t)BB * LL)      // 16809984

typedef unsigned short u16;
typedef __attribute__((ext_vector_type(8))) short s8v;     // 8 bf16 = 16 bytes = 8 u16
typedef __attribute__((ext_vector_type(4))) float f32x4;

__device__ __forceinline__ u16 bf16bits(float x) {
    __hip_bfloat16 h = __float2bfloat16(x);
    return *reinterpret_cast<u16*>(&h);
}

// ---------------------------------------------------------------- numpy-exact pairwise sums
__device__ __forceinline__ float npy_pw128(const float* a) {
    float r0 = 0.f, r1 = 0.f, r2 = 0.f, r3 = 0.f, r4 = 0.f, r5 = 0.f, r6 = 0.f, r7 = 0.f;
    for (int i = 0; i < 128; i += 8) {
        r0 += a[i + 0]; r1 += a[i + 1]; r2 += a[i + 2]; r3 += a[i + 3];
        r4 += a[i + 4]; r5 += a[i + 5]; r6 += a[i + 6]; r7 += a[i + 7];
    }
    return ((r0 + r1) + (r2 + r3)) + ((r4 + r5) + (r6 + r7));
}

__device__ __forceinline__ float npy_pw128_sq(const float* a) {
    float r0 = 0.f, r1 = 0.f, r2 = 0.f, r3 = 0.f, r4 = 0.f, r5 = 0.f, r6 = 0.f, r7 = 0.f;
    for (int i = 0; i < 128; i += 8) {
        float p0 = a[i + 0] * a[i + 0]; float p1 = a[i + 1] * a[i + 1];
        float p2 = a[i + 2] * a[i + 2]; float p3 = a[i + 3] * a[i + 3];
        float p4 = a[i + 4] * a[i + 4]; float p5 = a[i + 5] * a[i + 5];
        float p6 = a[i + 6] * a[i + 6]; float p7 = a[i + 7] * a[i + 7];
        r0 += p0; r1 += p1; r2 += p2; r3 += p3;
        r4 += p4; r5 += p5; r6 += p6; r7 += p7;
    }
    return ((r0 + r1) + (r2 + r3)) + ((r4 + r5) + (r6 + r7));
}

__device__ inline float breduce512_f32(float v, float* sbuf) {
    for (int off = 32; off > 0; off >>= 1) v += __shfl_down(v, off, 64);
    int wid = threadIdx.x >> 6;
    if ((threadIdx.x & 63) == 0) sbuf[wid] = v;
    __syncthreads();
    if (threadIdx.x == 0) {
        float r = 0.f;
#pragma unroll
        for (int i = 0; i < 8; ++i) r += sbuf[i];
        sbuf[0] = r;
    }
    __syncthreads();
    float r = sbuf[0];
    __syncthreads();
    return r;
}

__device__ inline double breduce256_f64(double v, double* dbuf) {
    for (int off = 32; off > 0; off >>= 1) v += __shfl_down(v, off, 64);
    int wid = threadIdx.x >> 6, lane = threadIdx.x & 63;
    if (lane == 0) dbuf[wid] = v;
    __syncthreads();
    if (threadIdx.x == 0) dbuf[0] = dbuf[0] + dbuf[1] + dbuf[2] + dbuf[3];
    __syncthreads();
    double r = dbuf[0];
    __syncthreads();
    return r;
}

// ---------------------------------------------------------------- prep (validated; + wo_bf bf16)
__global__ __launch_bounds__(256) void prep_kernel(const float* __restrict__ w_in,
                                                   const float* __restrict__ codebook,
                                                   const float* __restrict__ w_out,
                                                   float* __restrict__ whT,
                                                   float* __restrict__ cbn,
                                                   float* __restrict__ woT,
                                                   u16* __restrict__ wo_bf,
                                                   u16* __restrict__ cb_hi) {
    __shared__ float srow[512];
    __shared__ float sden;
    const int blk = blockIdx.x;
    const int t = threadIdx.x;
    if (blk < HH) {
        const float* row = w_in + (size_t)blk * DD;
        float a = row[t], b = row[t + 256];
        srow[t] = a * a;
        srow[t + 256] = b * b;
        __syncthreads();
        if (t == 0) {
            float ss = (npy_pw128(srow) + npy_pw128(srow + 128)) +
                       (npy_pw128(srow + 256) + npy_pw128(srow + 384));
            sden = sqrtf(ss) + FEPS;
        }
        __syncthreads();
        float den = sden;
        whT[(size_t)t * HH + blk] = a / den;
        whT[(size_t)(t + 256) * HH + blk] = b / den;
    } else if (blk < HH + DD) {
        const int d = blk - HH;
        const float* row = w_out + (size_t)d * HH;
        float a = row[t];
        srow[t] = a * a;
        __syncthreads();
        if (t == 0) {
            float ss = npy_pw128(srow) + npy_pw128(srow + 128);
            sden = sqrtf(ss) + FEPS;
        }
        __syncthreads();
        float v = a / sden;
        woT[(size_t)t * DD + d] = v;
        wo_bf[(size_t)d * HH + t] = bf16bits(v);   // row-major [d][k]
    } else {
        const int n = blk - HH - DD;
        const float* row = codebook + (size_t)n * HH;
        float a = row[t];
        srow[t] = a * a;
        __syncthreads();
        if (t == 0) {
            float ss = npy_pw128(srow) + npy_pw128(srow + 128);
            float m = ss / 256.0f;
            sden = 1.0f / sqrtf(m + FEPS);
        }
        __syncthreads();
        float v = a * sden;
        cbn[(size_t)n * HH + t] = v;
        cb_hi[(size_t)n * HH + t] = bf16bits(v);
    }
}

// ---------------------------------------------------------------- kernel A: exact h-GEMM, scalar-w / lane-unique-z
// (validated round-15)
__global__ __launch_bounds__(512, 4) void gemm_h_kernel(const float* __restrict__ z,
                                                        const float* __restrict__ whT,
                                                        float* __restrict__ hn) {
    __shared__ float z_lds[64 * 33];
    const int b = blockIdx.y;
    const int l0 = blockIdx.x * 64;
    const int t = threadIdx.x;
    const int lane = t & 63;
    const int bid = blockIdx.y * gridDim.x + blockIdx.x;
    const int hbase = __builtin_amdgcn_readfirstlane(t >> 6) * 32;
    const float* wbase = whT + hbase;

    float acc[32];
#pragma unroll
    for (int j = 0; j < 32; ++j) acc[j] = 0.f;

    const float* zb = z + (size_t)b * DD * LL;
    const int skk = t >> 4, sl4 = (t & 15) * 4;

    for (int kk0 = 0; kk0 < DD; kk0 += 32) {
        __syncthreads();
        {
            float4 gv = *(const float4*)(zb + (size_t)(kk0 + skk) * LL + l0 + sl4);
            z_lds[(sl4 + 0) * 33 + skk] = gv.x;
            z_lds[(sl4 + 1) * 33 + skk] = gv.y;
            z_lds[(sl4 + 2) * 33 + skk] = gv.z;
            z_lds[(sl4 + 3) * 33 + skk] = gv.w;
        }
        __syncthreads();
#pragma unroll
        for (int kt = 0; kt < 8; ++kt) {
            float4 zq = *(const float4*)&z_lds[lane * 33 + kt * 4];
#pragma unroll
            for (int k4 = 0; k4 < 4; ++k4) {
                float zv = (&zq.x)[k4];
                const float* wp = wbase + (size_t)(kk0 + kt * 4 + k4) * HH;
#pragma unroll
                for (int j = 0; j < 32; ++j)
                    acc[j] = fmaf(zv, wp[j], acc[j]);
            }
        }
    }

    const float SQ512 = sqrtf(512.0f);
    float* hb = hn + (size_t)bid * (64 * HH) + (size_t)lane * HH + hbase;
#pragma unroll
    for (int q = 0; q < 8; ++q) {
        float4 v;
        v.x = acc[q * 4 + 0] / SQ512;
        v.y = acc[q * 4 + 1] / SQ512;
        v.z = acc[q * 4 + 2] / SQ512;
        v.w = acc[q * 4 + 3] / SQ512;
        *(float4*)(hb + q * 4) = v;
    }
}

// ---------------------------------------------------------------- kernel B: rms + screen(4-pass prefetch) + verify + loss
// grid (LL/64, BB), 512 threads, 2 blocks/CU. Decision math bit-identical (rounds 7-15):
// same MFMA ops, same strict-> top-2 updates, same candidate rows -> identical cand set.
__global__ __launch_bounds__(512, 4) void select_kernel(const float* __restrict__ hn,
                                                        const float* __restrict__ cbn,
                                                        const u16* __restrict__ cb_hi,
                                                        int* __restrict__ inds_i,
                                                        float* __restrict__ partials) {
    __shared__ float hsm[64 * HST];     // 66,560 B
    __shared__ float cand_v[64][8][2];  // 4,096 (aliased: rtmp, scl, exv)
    __shared__ int   cand_i[64][8][2];  // 4,096
    __shared__ int   c4i[64][4];        // 1,024
    __shared__ int   ind_sm[64];        // 256
    __shared__ float sbuf[8];           // 32

    float* rtmp = &cand_v[0][0][0];
    float* scl  = &cand_v[0][0][0] + 128;
    float (*exv)[4] = (float(*)[4])&cand_v[0][0][0];

    const int b = blockIdx.y;
    const int l0 = blockIdx.x * 64;
    const int t = threadIdx.x;
    const int bid = blockIdx.y * gridDim.x + blockIdx.x;

    // ---------------- load hn block -> hsm (f32 bit-preserving)
    {
        int row = t >> 3, c0 = (t & 7) * 32;
        const float* src = hn + (size_t)bid * (64 * HH) + row * HH + c0;
        float* dst = &hsm[row * HST + c0];
#pragma unroll
        for (int q = 0; q < 8; ++q)
            *(float4*)(dst + q * 4) = *(const float4*)(src + q * 4);
    }
    __syncthreads();

    // ---------------- rms (npy pairwise, bit-exact) + scale in place
    if (t < 128) {
        int row = t >> 1, half = t & 1;
        rtmp[t] = npy_pw128_sq(&hsm[row * HST + half * 128]);
    }
    __syncthreads();
    if (t < 64) {
        float ss = rtmp[t * 2] + rtmp[t * 2 + 1];
        float m = ss / 256.0f;
        scl[t] = 1.0f / sqrtf(m + FEPS);
    }
    __syncthreads();
    {
        int row = t >> 3, c0 = (t & 7) * 32;
        float s = scl[row];
        float* hp = &hsm[row * HST + c0];
#pragma unroll
        for (int k = 0; k < 32; ++k) hp[k] = hp[k] * s;
    }
    __syncthreads();   // scl/rtmp dead; cand region free

    // ---------------- MFMA hi-only screen: 4 passes x 16 rows, next-it prefetch
    {
        const int lane = t & 63;
        const int wid = t >> 6;          // 8 waves, 256 codes each
        const int col = lane & 15;
        const int kg = lane >> 4;        // k = s*32 + kg*8 + e
#pragma unroll 1
        for (int pass = 0; pass < 4; ++pass) {
            const int rbase = pass * 16;
            s8v ah[8];
#pragma unroll
            for (int s = 0; s < 8; ++s) {
                const float* hp = &hsm[(rbase + col) * HST + s * 32 + kg * 8];
                float4 p = *(const float4*)hp;
                float4 q = *(const float4*)(hp + 4);
                s8v v;
                v[0] = (short)bf16bits(p.x); v[1] = (short)bf16bits(p.y);
                v[2] = (short)bf16bits(p.z); v[3] = (short)bf16bits(p.w);
                v[4] = (short)bf16bits(q.x); v[5] = (short)bf16bits(q.y);
                v[6] = (short)bf16bits(q.z); v[7] = (short)bf16bits(q.w);
                ah[s] = v;
            }
            float v0[4], v1[4]; int i0[4], i1[4];
#pragma unroll
            for (int j = 0; j < 4; ++j) {
                v0[j] = -3.4e38f; v1[j] = -3.4e38f;
                i0[j] = 0; i1[j] = 0;
            }
            // prefetch it=0
            s8v bh[8];
            {
                const u16* cbh = cb_hi + (size_t)(wid * 256 + col) * HH;
#pragma unroll
                for (int s = 0; s < 8; ++s)
                    bh[s] = *(const s8v*)(cbh + s * 32 + kg * 8);
            }
#pragma unroll 1
            for (int it = 0; it < 16; ++it) {
                s8v bhn[8];
                if (it < 15) {
                    const u16* cbhn = cb_hi + (size_t)((wid * 16 + it + 1) * 16 + col) * HH;
#pragma unroll
                    for (int s = 0; s < 8; ++s)
                        bhn[s] = *(const s8v*)(cbhn + s * 32 + kg * 8);
                }
                f32x4 a0 = {0.f, 0.f, 0.f, 0.f};
#pragma unroll
                for (int s = 0; s < 8; ++s)
                    a0 = __builtin_amdgcn_mfma_f32_16x16x32_bf16(ah[s], bh[s], a0, 0, 0, 0);
                const int n = (wid * 16 + it) * 16 + col;
#pragma unroll
                for (int j = 0; j < 4; ++j) {
                    float v = a0[j];
                    bool g0 = v > v0[j], g1 = v > v1[j];
                    v1[j] = g0 ? v0[j] : (g1 ? v : v1[j]);
                    i1[j] = g0 ? i0[j] : (g1 ? n : i1[j]);
                    v0[j] = g0 ? v : v0[j];
                    i0[j] = g0 ? n : i0[j];
                }
                if (it < 15) {
#pragma unroll
                    for (int s = 0; s < 8; ++s) bh[s] = bhn[s];
                }
            }
            // butterfly top-2 merge across the 16 col-lanes (identical to validated)
#pragma unroll
            for (int m = 1; m < 16; m <<= 1) {
#pragma unroll
                for (int j = 0; j < 4; ++j) {
                    float ov0 = __shfl_xor(v0[j], m, 16);
                    int   oi0 = __shfl_xor(i0[j], m, 16);
                    float ov1 = __shfl_xor(v1[j], m, 16);
                    int   oi1 = __shfl_xor(i1[j], m, 16);
                    bool a = ov0 > v0[j];
                    float w0 = a ? ov0 : v0[j]; int w0i = a ? oi0 : i0[j];
                    float s0 = a ? v0[j] : ov0; int s0i = a ? i0[j] : oi0;
                    bool bgt = ov1 > v1[j];
                    float w1 = bgt ? ov1 : v1[j]; int w1i = bgt ? oi1 : i1[j];
                    bool c2 = w1 > s0;
                    v0[j] = w0; i0[j] = w0i;
                    v1[j] = c2 ? w1 : s0; i1[j] = c2 ? w1i : s0i;
                }
            }
            if (col == 0) {
#pragma unroll
                for (int j = 0; j < 4; ++j) {
                    int row = rbase + kg * 4 + j;
                    cand_v[row][wid][0] = v0[j]; cand_i[row][wid][0] = i0[j];
                    cand_v[row][wid][1] = v1[j]; cand_i[row][wid][1] = i1[j];
                }
            }
        }
    }
    __syncthreads();

    // ---------------- per-row top-4 of 16, sorted by n ascending
    if (t < 64) {
        float vv[16]; int ii[16];
#pragma unroll
        for (int w = 0; w < 8; ++w) {
            vv[w * 2] = cand_v[t][w][0];     ii[w * 2] = cand_i[t][w][0];
            vv[w * 2 + 1] = cand_v[t][w][1]; ii[w * 2 + 1] = cand_i[t][w][1];
        }
        int sel[4];
#pragma unroll
        for (int c = 0; c < 4; ++c) {
            float bv = -3.4e38f; int bj = 0;
#pragma unroll
            for (int q = 0; q < 16; ++q)
                if (vv[q] > bv) { bv = vv[q]; bj = q; }
            sel[c] = ii[bj];
            vv[bj] = -3.4e38f;
        }
#pragma unroll
        for (int a = 0; a < 3; ++a)
#pragma unroll
            for (int bq = 0; bq < 3 - a; ++bq)
                if (sel[bq] > sel[bq + 1]) { int tmp = sel[bq]; sel[bq] = sel[bq + 1]; sel[bq + 1] = tmp; }
#pragma unroll
        for (int c = 0; c < 4; ++c) c4i[t][c] = sel[c];
    }
    __syncthreads();   // cand_v dead; exv alias live

    // ---------------- exact f32 seq-FMA verify (bit-identical chain)
    if (t < 256) {
        int row = t >> 2, c = t & 3;
        int n = c4i[row][c];
        const float* hr = &hsm[row * HST];
        const float* cr = cbn + (size_t)n * HH;
        float a0 = 0.f;
#pragma unroll 4
        for (int k = 0; k < HH; k += 4) {
            float4 cv = *(const float4*)(cr + k);
            float4 hv = *(const float4*)&hr[k];
            a0 = fmaf(hv.x, cv.x, a0); a0 = fmaf(hv.y, cv.y, a0);
            a0 = fmaf(hv.z, cv.z, a0); a0 = fmaf(hv.w, cv.w, a0);
        }
        exv[row][c] = a0;
    }
    __syncthreads();
    if (t < 64) {
        float bv = -3.4e38f; int bi = 0;
#pragma unroll
        for (int c = 0; c < 4; ++c) {
            float v = exv[t][c];
            int n = c4i[t][c];
            if (v > bv) { bv = v; bi = n; }   // candidates n-ascending; strict > = first max
        }
        ind_sm[t] = bi;
        inds_i[b * LL + l0 + t] = bi;
    }
    __syncthreads();

    // ---------------- loss partial (validated)
    {
        int rr = t >> 3, kg2 = t & 7;
        const float* cq2 = cbn + (size_t)ind_sm[rr] * HH;
        const float* hr = &hsm[rr * HST];
        float s = 0.f;
#pragma unroll
        for (int k = kg2 * 32; k < kg2 * 32 + 32; k += 4) {
            float4 cv = *(const float4*)(cq2 + k);
            float4 hv = *(const float4*)(hr + k);
            float e0 = cv.x - hv.x, e1 = cv.y - hv.y;
            float e2 = cv.z - hv.z, e3 = cv.w - hv.w;
            s = fmaf(e0, e0, s); s = fmaf(e1, e1, s);
            s = fmaf(e2, e2, s); s = fmaf(e3, e3, s);
        }
        s = breduce512_f32(s, sbuf);
        if (t == 0) partials[bid] = s;
    }
}

// ---------------------------------------------------------------- loss final (512 partials)
__global__ __launch_bounds__(256) void loss_final_kernel(const float* __restrict__ partials,
                                                         float* __restrict__ out_f32) {
    __shared__ double dbuf[8];
    const int t = threadIdx.x;
    double v = (double)partials[t] + (double)partials[t + 256];
    double s = breduce256_f64(v, dbuf);
    if (t == 0) {
        double mean = s / (double)((size_t)BB * LL * HH);
        out_f32[LOSS_OFF] = (float)(mean * 1.25);
    }
}

// ---------------------------------------------------------------- inds epilogue
__global__ __launch_bounds__(256) void epilogue_kernel(const int* __restrict__ inds_i,
                                                       float* __restrict__ out_f32) {
    int idx = blockIdx.x * 256 + threadIdx.x;
    if (idx < BB * LL) out_f32[IND_OFF + idx] = (float)inds_i[idx];
}

// ---------------------------------------------------------------- gemm_out: bf16 MFMA (STAGING STRIDE FIXED)
// grid (LL/64, DD/64, BB), 256 threads = 4 waves; wave owns 16 d x 64 l.
// Layout identical to the screen-validated MFMA mapping. Threshold 40.96 >> bf16 err.
__global__ __launch_bounds__(256, 4) void gemm_out_kernel(const u16* __restrict__ cb_hi,
                                                          const int* __restrict__ inds_i,
                                                          const u16* __restrict__ wo_bf,
                                                          float* __restrict__ out_f32) {
    __shared__ alignas(16) u16 zq[64 * 264];   // gathered z_q rows, bf16
    __shared__ int inds_s[64];
    const int b = blockIdx.z;
    const int d0 = blockIdx.y * 64;
    const int l0 = blockIdx.x * 64;
    const int t = threadIdx.x;
    if (t < 64) {
        int ii = inds_i[b * LL + l0 + t];
        inds_s[t] = min(max(ii, 0), NN - 1);
    }
    __syncthreads();
    {   // stage: thread copies its 64-u16 quarter with EIGHT 8-u16 (16B) stores
        int li = t >> 2, qt = t & 3;
        const u16* src = cb_hi + (size_t)inds_s[li] * HH + qt * 64;
        u16* dst = &zq[li * 264 + qt * 64];
#pragma unroll
        for (int q = 0; q < 8; ++q)      // FIX: was q<4, stride 16 (halved coverage -> stale LDS -> NaN)
            *(s8v*)(dst + q * 8) = *(const s8v*)(src + q * 8);
    }
    __syncthreads();

    const int lane = t & 63;
    const int wid = t >> 6;          // 4 waves -> d slice d0 + wid*16
    const int col = lane & 15;
    const int kg = lane >> 4;
    s8v aw[8];
    {
        const u16* wp = wo_bf + (size_t)(d0 + wid * 16 + col) * HH;
#pragma unroll
        for (int s = 0; s < 8; ++s)
            aw[s] = *(const s8v*)(wp + s * 32 + kg * 8);
    }
#pragma unroll
    for (int lt = 0; lt < 4; ++lt) {
        f32x4 c = {0.f, 0.f, 0.f, 0.f};
#pragma unroll
        for (int s = 0; s < 8; ++s) {
            s8v bz = *(const s8v*)&zq[(lt * 16 + col) * 264 + s * 32 + kg * 8];
            c = __builtin_amdgcn_mfma_f32_16x16x32_bf16(aw[s], bz, c, 0, 0, 0);
        }
        int l = l0 + lt * 16 + col;
#pragma unroll
        for (int j = 0; j < 4; ++j) {
            int d = d0 + wid * 16 + kg * 4 + j;
            out_f32[((size_t)b * DD + d) * LL + l] = c[j] * 0.0625f;   // /sqrt(256) == /16 exact
        }
    }
}

extern "C" void kernel_launch(void* const* d_in, const int* in_sizes, int n_in,
                              void* d_out, int out_size, void* d_ws, size_t ws_size,
                              hipStream_t stream) {
    const float* z        = (const float*)d_in[0];
    const float* w_in     = (const float*)d_in[1];
    const float* codebook = (const float*)d_in[2];
    const float* w_out    = (const float*)d_in[3];

    char* ws = (char*)d_ws;
    size_t off = 0;
    float* whT = (float*)(ws + off); off += (size_t)DD * HH * 4;        // 512 KB
    float* cbn = (float*)(ws + off); off += (size_t)NN * HH * 4;        // 2 MB
    float* woT = (float*)(ws + off); off += (size_t)HH * DD * 4;        // 512 KB (revert safety)
    int* inds_i = (int*)(ws + off);  off += (size_t)BB * LL * 4;        // 128 KB
    float* partials = (float*)(ws + off); off += 512 * 4;               // 2 KB
    u16* cb_hi = (u16*)(ws + off); off += (size_t)NN * HH * 2;          // 1 MB
    u16* wo_bf = (u16*)(ws + off); off += (size_t)DD * HH * 2;          // 256 KB
    float* hn = (float*)(ws + off); off += (size_t)BB * LL * HH * 4;    // 32 MB

    float* out_f32 = (float*)d_out;

    prep_kernel<<<HH + DD + NN, 256, 0, stream>>>(w_in, codebook, w_out, whT, cbn, woT, wo_bf, cb_hi);
    gemm_h_kernel<<<dim3(LL / 64, BB), 512, 0, stream>>>(z, whT, hn);
    select_kernel<<<dim3(LL / 64, BB), 512, 0, stream>>>(hn, cbn, cb_hi, inds_i, partials);
    loss_final_kernel<<<1, 256, 0, stream>>>(partials, out_f32);
    epilogue_kernel<<<(BB * LL + 255) / 256, 256, 0, stream>>>(inds_i, out_f32);
    gemm_out_kernel<<<dim3(LL / 64, DD / 64, BB), 256, 0, stream>>>(cb_hi, inds_i, wo_bf, out_f32);
}

// Round 18
// 423.962 us; speedup vs baseline: 1.0441x; 1.0441x over previous
//
#include <hip/hip_runtime.h>
#include <hip/hip_bf16.h>

#pragma clang fp contract(off)

#define BB 8
#define DD 512
#define LL 4096
#define HH 256
#define NN 2048
#define FEPS 1.1920928955078125e-07f
#define HST 260   // hsm row stride (words): 260%32=4 -> 2-way bank aliasing (free)

#define IND_OFF ((size_t)BB * DD * LL)            // 16777216
#define LOSS_OFF (IND_OFF + (size_t)BB * LL)      // 16809984

typedef unsigned short u16;
typedef __attribute__((ext_vector_type(8))) short s8v;     // 8 bf16 = 16 bytes = 8 u16
typedef __attribute__((ext_vector_type(4))) float f32x4;

__device__ __forceinline__ u16 bf16bits(float x) {
    __hip_bfloat16 h = __float2bfloat16(x);
    return *reinterpret_cast<u16*>(&h);
}

// ---------------------------------------------------------------- numpy-exact pairwise sums
__device__ __forceinline__ float npy_pw128(const float* a) {
    float r0 = 0.f, r1 = 0.f, r2 = 0.f, r3 = 0.f, r4 = 0.f, r5 = 0.f, r6 = 0.f, r7 = 0.f;
    for (int i = 0; i < 128; i += 8) {
        r0 += a[i + 0]; r1 += a[i + 1]; r2 += a[i + 2]; r3 += a[i + 3];
        r4 += a[i + 4]; r5 += a[i + 5]; r6 += a[i + 6]; r7 += a[i + 7];
    }
    return ((r0 + r1) + (r2 + r3)) + ((r4 + r5) + (r6 + r7));
}

__device__ __forceinline__ float npy_pw128_sq(const float* a) {
    float r0 = 0.f, r1 = 0.f, r2 = 0.f, r3 = 0.f, r4 = 0.f, r5 = 0.f, r6 = 0.f, r7 = 0.f;
    for (int i = 0; i < 128; i += 8) {
        float p0 = a[i + 0] * a[i + 0]; float p1 = a[i + 1] * a[i + 1];
        float p2 = a[i + 2] * a[i + 2]; float p3 = a[i + 3] * a[i + 3];
        float p4 = a[i + 4] * a[i + 4]; float p5 = a[i + 5] * a[i + 5];
        float p6 = a[i + 6] * a[i + 6]; float p7 = a[i + 7] * a[i + 7];
        r0 += p0; r1 += p1; r2 += p2; r3 += p3;
        r4 += p4; r5 += p5; r6 += p6; r7 += p7;
    }
    return ((r0 + r1) + (r2 + r3)) + ((r4 + r5) + (r6 + r7));
}

__device__ inline float breduce512_f32(float v, float* sbuf) {
    for (int off = 32; off > 0; off >>= 1) v += __shfl_down(v, off, 64);
    int wid = threadIdx.x >> 6;
    if ((threadIdx.x & 63) == 0) sbuf[wid] = v;
    __syncthreads();
    if (threadIdx.x == 0) {
        float r = 0.f;
#pragma unroll
        for (int i = 0; i < 8; ++i) r += sbuf[i];
        sbuf[0] = r;
    }
    __syncthreads();
    float r = sbuf[0];
    __syncthreads();
    return r;
}

__device__ inline double breduce256_f64(double v, double* dbuf) {
    for (int off = 32; off > 0; off >>= 1) v += __shfl_down(v, off, 64);
    int wid = threadIdx.x >> 6, lane = threadIdx.x & 63;
    if (lane == 0) dbuf[wid] = v;
    __syncthreads();
    if (threadIdx.x == 0) dbuf[0] = dbuf[0] + dbuf[1] + dbuf[2] + dbuf[3];
    __syncthreads();
    double r = dbuf[0];
    __syncthreads();
    return r;
}

// ---------------------------------------------------------------- prep (validated; + wo_bf bf16)
__global__ __launch_bounds__(256) void prep_kernel(const float* __restrict__ w_in,
                                                   const float* __restrict__ codebook,
                                                   const float* __restrict__ w_out,
                                                   float* __restrict__ whT,
                                                   float* __restrict__ cbn,
                                                   u16* __restrict__ wo_bf,
                                                   u16* __restrict__ cb_hi) {
    __shared__ float srow[512];
    __shared__ float sden;
    const int blk = blockIdx.x;
    const int t = threadIdx.x;
    if (blk < HH) {
        const float* row = w_in + (size_t)blk * DD;
        float a = row[t], b = row[t + 256];
        srow[t] = a * a;
        srow[t + 256] = b * b;
        __syncthreads();
        if (t == 0) {
            float ss = (npy_pw128(srow) + npy_pw128(srow + 128)) +
                       (npy_pw128(srow + 256) + npy_pw128(srow + 384));
            sden = sqrtf(ss) + FEPS;
        }
        __syncthreads();
        float den = sden;
        whT[(size_t)t * HH + blk] = a / den;
        whT[(size_t)(t + 256) * HH + blk] = b / den;
    } else if (blk < HH + DD) {
        const int d = blk - HH;
        const float* row = w_out + (size_t)d * HH;
        float a = row[t];
        srow[t] = a * a;
        __syncthreads();
        if (t == 0) {
            float ss = npy_pw128(srow) + npy_pw128(srow + 128);
            sden = sqrtf(ss) + FEPS;
        }
        __syncthreads();
        wo_bf[(size_t)d * HH + t] = bf16bits(a / sden);   // row-major [d][k]
    } else {
        const int n = blk - HH - DD;
        const float* row = codebook + (size_t)n * HH;
        float a = row[t];
        srow[t] = a * a;
        __syncthreads();
        if (t == 0) {
            float ss = npy_pw128(srow) + npy_pw128(srow + 128);
            float m = ss / 256.0f;
            sden = 1.0f / sqrtf(m + FEPS);
        }
        __syncthreads();
        float v = a * sden;
        cbn[(size_t)n * HH + t] = v;
        cb_hi[(size_t)n * HH + t] = bf16bits(v);
    }
}

// ---------------------------------------------------------------- kernel A: exact h-GEMM, scalar-w / lane-unique-z
// (validated round-15)
__global__ __launch_bounds__(512, 4) void gemm_h_kernel(const float* __restrict__ z,
                                                        const float* __restrict__ whT,
                                                        float* __restrict__ hn) {
    __shared__ float z_lds[64 * 33];
    const int b = blockIdx.y;
    const int l0 = blockIdx.x * 64;
    const int t = threadIdx.x;
    const int lane = t & 63;
    const int bid = blockIdx.y * gridDim.x + blockIdx.x;
    const int hbase = __builtin_amdgcn_readfirstlane(t >> 6) * 32;
    const float* wbase = whT + hbase;

    float acc[32];
#pragma unroll
    for (int j = 0; j < 32; ++j) acc[j] = 0.f;

    const float* zb = z + (size_t)b * DD * LL;
    const int skk = t >> 4, sl4 = (t & 15) * 4;

    for (int kk0 = 0; kk0 < DD; kk0 += 32) {
        __syncthreads();
        {
            float4 gv = *(const float4*)(zb + (size_t)(kk0 + skk) * LL + l0 + sl4);
            z_lds[(sl4 + 0) * 33 + skk] = gv.x;
            z_lds[(sl4 + 1) * 33 + skk] = gv.y;
            z_lds[(sl4 + 2) * 33 + skk] = gv.z;
            z_lds[(sl4 + 3) * 33 + skk] = gv.w;
        }
        __syncthreads();
#pragma unroll
        for (int kt = 0; kt < 8; ++kt) {
            float4 zq = *(const float4*)&z_lds[lane * 33 + kt * 4];
#pragma unroll
            for (int k4 = 0; k4 < 4; ++k4) {
                float zv = (&zq.x)[k4];
                const float* wp = wbase + (size_t)(kk0 + kt * 4 + k4) * HH;
#pragma unroll
                for (int j = 0; j < 32; ++j)
                    acc[j] = fmaf(zv, wp[j], acc[j]);
            }
        }
    }

    const float SQ512 = sqrtf(512.0f);
    float* hb = hn + (size_t)bid * (64 * HH) + (size_t)lane * HH + hbase;
#pragma unroll
    for (int q = 0; q < 8; ++q) {
        float4 v;
        v.x = acc[q * 4 + 0] / SQ512;
        v.y = acc[q * 4 + 1] / SQ512;
        v.z = acc[q * 4 + 2] / SQ512;
        v.w = acc[q * 4 + 3] / SQ512;
        *(float4*)(hb + q * 4) = v;
    }
}

// ---------------------------------------------------------------- kernel B: rms + screen + verify + loss
// ROUND-15 VERBATIM (measured 172 us). Decision math bit-identical (rounds 7-15).
__global__ __launch_bounds__(512, 4) void select_kernel(const float* __restrict__ hn,
                                                        const float* __restrict__ cbn,
                                                        const u16* __restrict__ cb_hi,
                                                        int* __restrict__ inds_i,
                                                        float* __restrict__ partials) {
    __shared__ float hsm[64 * HST];     // 66,560 B
    __shared__ float cand_v[64][8][2];  // 4,096 (aliased: rtmp, scl, exv)
    __shared__ int   cand_i[64][8][2];  // 4,096
    __shared__ int   c4i[64][4];        // 1,024
    __shared__ int   ind_sm[64];        // 256
    __shared__ float sbuf[8];           // 32

    float* rtmp = &cand_v[0][0][0];
    float* scl  = &cand_v[0][0][0] + 128;
    float (*exv)[4] = (float(*)[4])&cand_v[0][0][0];

    const int b = blockIdx.y;
    const int l0 = blockIdx.x * 64;
    const int t = threadIdx.x;
    const int bid = blockIdx.y * gridDim.x + blockIdx.x;

    // ---------------- load hn block -> hsm (f32 bit-preserving)
    {
        int row = t >> 3, c0 = (t & 7) * 32;
        const float* src = hn + (size_t)bid * (64 * HH) + row * HH + c0;
        float* dst = &hsm[row * HST + c0];
#pragma unroll
        for (int q = 0; q < 8; ++q)
            *(float4*)(dst + q * 4) = *(const float4*)(src + q * 4);
    }
    __syncthreads();

    // ---------------- rms (npy pairwise, bit-exact) + scale in place
    if (t < 128) {
        int row = t >> 1, half = t & 1;
        rtmp[t] = npy_pw128_sq(&hsm[row * HST + half * 128]);
    }
    __syncthreads();
    if (t < 64) {
        float ss = rtmp[t * 2] + rtmp[t * 2 + 1];
        float m = ss / 256.0f;
        scl[t] = 1.0f / sqrtf(m + FEPS);
    }
    __syncthreads();
    {
        int row = t >> 3, c0 = (t & 7) * 32;
        float s = scl[row];
        float* hp = &hsm[row * HST + c0];
#pragma unroll
        for (int k = 0; k < 32; ++k) hp[k] = hp[k] * s;
    }
    __syncthreads();   // scl/rtmp dead; cand region free

    // ---------------- MFMA hi-only screen: 4 passes x 16 rows (round-15 verbatim)
    {
        const int lane = t & 63;
        const int wid = t >> 6;          // 8 waves, 256 codes each
        const int col = lane & 15;
        const int kg = lane >> 4;        // k = s*32 + kg*8 + e
#pragma unroll 1
        for (int pass = 0; pass < 4; ++pass) {
            const int rbase = pass * 16;
            s8v ah[8];
#pragma unroll
            for (int s = 0; s < 8; ++s) {
                const float* hp = &hsm[(rbase + col) * HST + s * 32 + kg * 8];
                float4 p = *(const float4*)hp;
                float4 q = *(const float4*)(hp + 4);
                s8v v;
                v[0] = (short)bf16bits(p.x); v[1] = (short)bf16bits(p.y);
                v[2] = (short)bf16bits(p.z); v[3] = (short)bf16bits(p.w);
                v[4] = (short)bf16bits(q.x); v[5] = (short)bf16bits(q.y);
                v[6] = (short)bf16bits(q.z); v[7] = (short)bf16bits(q.w);
                ah[s] = v;
            }
            float v0[4], v1[4]; int i0[4], i1[4];
#pragma unroll
            for (int j = 0; j < 4; ++j) {
                v0[j] = -3.4e38f; v1[j] = -3.4e38f;
                i0[j] = 0; i1[j] = 0;
            }
#pragma unroll 1
            for (int it = 0; it < 16; ++it) {
                const int n0 = (wid * 16 + it) * 16;
                const u16* cbh = cb_hi + (size_t)(n0 + col) * HH;
                f32x4 a0 = {0.f, 0.f, 0.f, 0.f};
#pragma unroll
                for (int s = 0; s < 8; ++s) {
                    s8v bh = *(const s8v*)(cbh + s * 32 + kg * 8);
                    a0 = __builtin_amdgcn_mfma_f32_16x16x32_bf16(ah[s], bh, a0, 0, 0, 0);
                }
                const int n = n0 + col;
#pragma unroll
                for (int j = 0; j < 4; ++j) {
                    float v = a0[j];
                    bool g0 = v > v0[j], g1 = v > v1[j];
                    v1[j] = g0 ? v0[j] : (g1 ? v : v1[j]);
                    i1[j] = g0 ? i0[j] : (g1 ? n : i1[j]);
                    v0[j] = g0 ? v : v0[j];
                    i0[j] = g0 ? n : i0[j];
                }
            }
            // butterfly top-2 merge across the 16 col-lanes
#pragma unroll
            for (int m = 1; m < 16; m <<= 1) {
#pragma unroll
                for (int j = 0; j < 4; ++j) {
                    float ov0 = __shfl_xor(v0[j], m, 16);
                    int   oi0 = __shfl_xor(i0[j], m, 16);
                    float ov1 = __shfl_xor(v1[j], m, 16);
                    int   oi1 = __shfl_xor(i1[j], m, 16);
                    bool a = ov0 > v0[j];
                    float w0 = a ? ov0 : v0[j]; int w0i = a ? oi0 : i0[j];
                    float s0 = a ? v0[j] : ov0; int s0i = a ? i0[j] : oi0;
                    bool bgt = ov1 > v1[j];
                    float w1 = bgt ? ov1 : v1[j]; int w1i = bgt ? oi1 : i1[j];
                    bool c2 = w1 > s0;
                    v0[j] = w0; i0[j] = w0i;
                    v1[j] = c2 ? w1 : s0; i1[j] = c2 ? w1i : s0i;
                }
            }
            if (col == 0) {
#pragma unroll
                for (int j = 0; j < 4; ++j) {
                    int row = rbase + kg * 4 + j;
                    cand_v[row][wid][0] = v0[j]; cand_i[row][wid][0] = i0[j];
                    cand_v[row][wid][1] = v1[j]; cand_i[row][wid][1] = i1[j];
                }
            }
        }
    }
    __syncthreads();

    // ---------------- per-row top-4 of 16, sorted by n ascending
    if (t < 64) {
        float vv[16]; int ii[16];
#pragma unroll
        for (int w = 0; w < 8; ++w) {
            vv[w * 2] = cand_v[t][w][0];     ii[w * 2] = cand_i[t][w][0];
            vv[w * 2 + 1] = cand_v[t][w][1]; ii[w * 2 + 1] = cand_i[t][w][1];
        }
        int sel[4];
#pragma unroll
        for (int c = 0; c < 4; ++c) {
            float bv = -3.4e38f; int bj = 0;
#pragma unroll
            for (int q = 0; q < 16; ++q)
                if (vv[q] > bv) { bv = vv[q]; bj = q; }
            sel[c] = ii[bj];
            vv[bj] = -3.4e38f;
        }
#pragma unroll
        for (int a = 0; a < 3; ++a)
#pragma unroll
            for (int bq = 0; bq < 3 - a; ++bq)
                if (sel[bq] > sel[bq + 1]) { int tmp = sel[bq]; sel[bq] = sel[bq + 1]; sel[bq + 1] = tmp; }
#pragma unroll
        for (int c = 0; c < 4; ++c) c4i[t][c] = sel[c];
    }
    __syncthreads();   // cand_v dead; exv alias live

    // ---------------- exact f32 seq-FMA verify (bit-identical chain)
    if (t < 256) {
        int row = t >> 2, c = t & 3;
        int n = c4i[row][c];
        const float* hr = &hsm[row * HST];
        const float* cr = cbn + (size_t)n * HH;
        float a0 = 0.f;
#pragma unroll 4
        for (int k = 0; k < HH; k += 4) {
            float4 cv = *(const float4*)(cr + k);
            float4 hv = *(const float4*)&hr[k];
            a0 = fmaf(hv.x, cv.x, a0); a0 = fmaf(hv.y, cv.y, a0);
            a0 = fmaf(hv.z, cv.z, a0); a0 = fmaf(hv.w, cv.w, a0);
        }
        exv[row][c] = a0;
    }
    __syncthreads();
    if (t < 64) {
        float bv = -3.4e38f; int bi = 0;
#pragma unroll
        for (int c = 0; c < 4; ++c) {
            float v = exv[t][c];
            int n = c4i[t][c];
            if (v > bv) { bv = v; bi = n; }   // candidates n-ascending; strict > = first max
        }
        ind_sm[t] = bi;
        inds_i[b * LL + l0 + t] = bi;
    }
    __syncthreads();

    // ---------------- loss partial (validated)
    {
        int rr = t >> 3, kg2 = t & 7;
        const float* cq2 = cbn + (size_t)ind_sm[rr] * HH;
        const float* hr = &hsm[rr * HST];
        float s = 0.f;
#pragma unroll
        for (int k = kg2 * 32; k < kg2 * 32 + 32; k += 4) {
            float4 cv = *(const float4*)(cq2 + k);
            float4 hv = *(const float4*)(hr + k);
            float e0 = cv.x - hv.x, e1 = cv.y - hv.y;
            float e2 = cv.z - hv.z, e3 = cv.w - hv.w;
            s = fmaf(e0, e0, s); s = fmaf(e1, e1, s);
            s = fmaf(e2, e2, s); s = fmaf(e3, e3, s);
        }
        s = breduce512_f32(s, sbuf);
        if (t == 0) partials[bid] = s;
    }
}

// ---------------------------------------------------------------- loss final (512 partials)
__global__ __launch_bounds__(256) void loss_final_kernel(const float* __restrict__ partials,
                                                         float* __restrict__ out_f32) {
    __shared__ double dbuf[8];
    const int t = threadIdx.x;
    double v = (double)partials[t] + (double)partials[t + 256];
    double s = breduce256_f64(v, dbuf);
    if (t == 0) {
        double mean = s / (double)((size_t)BB * LL * HH);
        out_f32[LOSS_OFF] = (float)(mean * 1.25);
    }
}

// ---------------------------------------------------------------- inds epilogue
__global__ __launch_bounds__(256) void epilogue_kernel(const int* __restrict__ inds_i,
                                                       float* __restrict__ out_f32) {
    int idx = blockIdx.x * 256 + threadIdx.x;
    if (idx < BB * LL) out_f32[IND_OFF + idx] = (float)inds_i[idx];
}

// ---------------------------------------------------------------- gemm_out: bf16 MFMA (validated round-17)
__global__ __launch_bounds__(256, 4) void gemm_out_kernel(const u16* __restrict__ cb_hi,
                                                          const int* __restrict__ inds_i,
                                                          const u16* __restrict__ wo_bf,
                                                          float* __restrict__ out_f32) {
    __shared__ alignas(16) u16 zq[64 * 264];   // gathered z_q rows, bf16
    __shared__ int inds_s[64];
    const int b = blockIdx.z;
    const int d0 = blockIdx.y * 64;
    const int l0 = blockIdx.x * 64;
    const int t = threadIdx.x;
    if (t < 64) {
        int ii = inds_i[b * LL + l0 + t];
        inds_s[t] = min(max(ii, 0), NN - 1);
    }
    __syncthreads();
    {   // stage: thread copies its 64-u16 quarter with eight 16B stores
        int li = t >> 2, qt = t & 3;
        const u16* src = cb_hi + (size_t)inds_s[li] * HH + qt * 64;
        u16* dst = &zq[li * 264 + qt * 64];
#pragma unroll
        for (int q = 0; q < 8; ++q)
            *(s8v*)(dst + q * 8) = *(const s8v*)(src + q * 8);
    }
    __syncthreads();

    const int lane = t & 63;
    const int wid = t >> 6;          // 4 waves -> d slice d0 + wid*16
    const int col = lane & 15;
    const int kg = lane >> 4;
    s8v aw[8];
    {
        const u16* wp = wo_bf + (size_t)(d0 + wid * 16 + col) * HH;
#pragma unroll
        for (int s = 0; s < 8; ++s)
            aw[s] = *(const s8v*)(wp + s * 32 + kg * 8);
    }
#pragma unroll
    for (int lt = 0; lt < 4; ++lt) {
        f32x4 c = {0.f, 0.f, 0.f, 0.f};
#pragma unroll
        for (int s = 0; s < 8; ++s) {
            s8v bz = *(const s8v*)&zq[(lt * 16 + col) * 264 + s * 32 + kg * 8];
            c = __builtin_amdgcn_mfma_f32_16x16x32_bf16(aw[s], bz, c, 0, 0, 0);
        }
        int l = l0 + lt * 16 + col;
#pragma unroll
        for (int j = 0; j < 4; ++j) {
            int d = d0 + wid * 16 + kg * 4 + j;
            out_f32[((size_t)b * DD + d) * LL + l] = c[j] * 0.0625f;   // /sqrt(256) == /16 exact
        }
    }
}

extern "C" void kernel_launch(void* const* d_in, const int* in_sizes, int n_in,
                              void* d_out, int out_size, void* d_ws, size_t ws_size,
                              hipStream_t stream) {
    const float* z        = (const float*)d_in[0];
    const float* w_in     = (const float*)d_in[1];
    const float* codebook = (const float*)d_in[2];
    const float* w_out    = (const float*)d_in[3];

    char* ws = (char*)d_ws;
    size_t off = 0;
    float* whT = (float*)(ws + off); off += (size_t)DD * HH * 4;        // 512 KB
    float* cbn = (float*)(ws + off); off += (size_t)NN * HH * 4;        // 2 MB
    int* inds_i = (int*)(ws + off);  off += (size_t)BB * LL * 4;        // 128 KB
    float* partials = (float*)(ws + off); off += 512 * 4;               // 2 KB
    u16* cb_hi = (u16*)(ws + off); off += (size_t)NN * HH * 2;          // 1 MB
    u16* wo_bf = (u16*)(ws + off); off += (size_t)DD * HH * 2;          // 256 KB
    float* hn = (float*)(ws + off); off += (size_t)BB * LL * HH * 4;    // 32 MB

    float* out_f32 = (float*)d_out;

    prep_kernel<<<HH + DD + NN, 256, 0, stream>>>(w_in, codebook, w_out, whT, cbn, wo_bf, cb_hi);
    gemm_h_kernel<<<dim3(LL / 64, BB), 512, 0, stream>>>(z, whT, hn);
    select_kernel<<<dim3(LL / 64, BB), 512, 0, stream>>>(hn, cbn, cb_hi, inds_i, partials);
    loss_final_kernel<<<1, 256, 0, stream>>>(partials, out_f32);
    epilogue_kernel<<<(BB * LL + 255) / 256, 256, 0, stream>>>(inds_i, out_f32);
    gemm_out_kernel<<<dim3(LL / 64, DD / 64, BB), 256, 0, stream>>>(cb_hi, inds_i, wo_bf, out_f32);
}

// Round 19
// 317.339 us; speedup vs baseline: 1.3948x; 1.3360x over previous
//
#include <hip/hip_runtime.h>
#include <hip/hip_bf16.h>

#pragma clang fp contract(off)

#define BB 8
#define DD 512
#define LL 4096
#define HH 256
#define NN 2048
#define FEPS 1.1920928955078125e-07f
#define HST 260   // hsm row stride (words): 260%32=4 -> 2-way bank aliasing (free)

#define IND_OFF ((size_t)BB * DD * LL)            // 16777216
#define LOSS_OFF (IND_OFF + (size_t)BB * LL)      // 16809984

typedef unsigned short u16;
typedef __attribute__((ext_vector_type(8))) short s8v;     // 8 bf16 = 16 bytes = 8 u16
typedef __attribute__((ext_vector_type(4))) float f32x4;

__device__ __forceinline__ u16 bf16bits(float x) {
    __hip_bfloat16 h = __float2bfloat16(x);
    return *reinterpret_cast<u16*>(&h);
}

// ---------------------------------------------------------------- numpy-exact pairwise sums
__device__ __forceinline__ float npy_pw128(const float* a) {
    float r0 = 0.f, r1 = 0.f, r2 = 0.f, r3 = 0.f, r4 = 0.f, r5 = 0.f, r6 = 0.f, r7 = 0.f;
    for (int i = 0; i < 128; i += 8) {
        r0 += a[i + 0]; r1 += a[i + 1]; r2 += a[i + 2]; r3 += a[i + 3];
        r4 += a[i + 4]; r5 += a[i + 5]; r6 += a[i + 6]; r7 += a[i + 7];
    }
    return ((r0 + r1) + (r2 + r3)) + ((r4 + r5) + (r6 + r7));
}

__device__ __forceinline__ float npy_pw128_sq(const float* a) {
    float r0 = 0.f, r1 = 0.f, r2 = 0.f, r3 = 0.f, r4 = 0.f, r5 = 0.f, r6 = 0.f, r7 = 0.f;
    for (int i = 0; i < 128; i += 8) {
        float p0 = a[i + 0] * a[i + 0]; float p1 = a[i + 1] * a[i + 1];
        float p2 = a[i + 2] * a[i + 2]; float p3 = a[i + 3] * a[i + 3];
        float p4 = a[i + 4] * a[i + 4]; float p5 = a[i + 5] * a[i + 5];
        float p6 = a[i + 6] * a[i + 6]; float p7 = a[i + 7] * a[i + 7];
        r0 += p0; r1 += p1; r2 += p2; r3 += p3;
        r4 += p4; r5 += p5; r6 += p6; r7 += p7;
    }
    return ((r0 + r1) + (r2 + r3)) + ((r4 + r5) + (r6 + r7));
}

__device__ inline float breduce512_f32(float v, float* sbuf) {
    for (int off = 32; off > 0; off >>= 1) v += __shfl_down(v, off, 64);
    int wid = threadIdx.x >> 6;
    if ((threadIdx.x & 63) == 0) sbuf[wid] = v;
    __syncthreads();
    if (threadIdx.x == 0) {
        float r = 0.f;
#pragma unroll
        for (int i = 0; i < 8; ++i) r += sbuf[i];
        sbuf[0] = r;
    }
    __syncthreads();
    float r = sbuf[0];
    __syncthreads();
    return r;
}

__device__ inline double breduce256_f64(double v, double* dbuf) {
    for (int off = 32; off > 0; off >>= 1) v += __shfl_down(v, off, 64);
    int wid = threadIdx.x >> 6, lane = threadIdx.x & 63;
    if (lane == 0) dbuf[wid] = v;
    __syncthreads();
    if (threadIdx.x == 0) dbuf[0] = dbuf[0] + dbuf[1] + dbuf[2] + dbuf[3];
    __syncthreads();
    double r = dbuf[0];
    __syncthreads();
    return r;
}

// ---------------------------------------------------------------- prep (validated; + wo_bf bf16)
__global__ __launch_bounds__(256) void prep_kernel(const float* __restrict__ w_in,
                                                   const float* __restrict__ codebook,
                                                   const float* __restrict__ w_out,
                                                   float* __restrict__ whT,
                                                   float* __restrict__ cbn,
                                                   u16* __restrict__ wo_bf,
                                                   u16* __restrict__ cb_hi) {
    __shared__ float srow[512];
    __shared__ float sden;
    const int blk = blockIdx.x;
    const int t = threadIdx.x;
    if (blk < HH) {
        const float* row = w_in + (size_t)blk * DD;
        float a = row[t], b = row[t + 256];
        srow[t] = a * a;
        srow[t + 256] = b * b;
        __syncthreads();
        if (t == 0) {
            float ss = (npy_pw128(srow) + npy_pw128(srow + 128)) +
                       (npy_pw128(srow + 256) + npy_pw128(srow + 384));
            sden = sqrtf(ss) + FEPS;
        }
        __syncthreads();
        float den = sden;
        whT[(size_t)t * HH + blk] = a / den;
        whT[(size_t)(t + 256) * HH + blk] = b / den;
    } else if (blk < HH + DD) {
        const int d = blk - HH;
        const float* row = w_out + (size_t)d * HH;
        float a = row[t];
        srow[t] = a * a;
        __syncthreads();
        if (t == 0) {
            float ss = npy_pw128(srow) + npy_pw128(srow + 128);
            sden = sqrtf(ss) + FEPS;
        }
        __syncthreads();
        wo_bf[(size_t)d * HH + t] = bf16bits(a / sden);   // row-major [d][k]
    } else {
        const int n = blk - HH - DD;
        const float* row = codebook + (size_t)n * HH;
        float a = row[t];
        srow[t] = a * a;
        __syncthreads();
        if (t == 0) {
            float ss = npy_pw128(srow) + npy_pw128(srow + 128);
            float m = ss / 256.0f;
            sden = 1.0f / sqrtf(m + FEPS);
        }
        __syncthreads();
        float v = a * sden;
        cbn[(size_t)n * HH + t] = v;
        cb_hi[(size_t)n * HH + t] = bf16bits(v);
    }
}

// ---------------------------------------------------------------- kernel A: exact h-GEMM, scalar-w / lane-unique-z
// (validated round-15)
__global__ __launch_bounds__(512, 4) void gemm_h_kernel(const float* __restrict__ z,
                                                        const float* __restrict__ whT,
                                                        float* __restrict__ hn) {
    __shared__ float z_lds[64 * 33];
    const int b = blockIdx.y;
    const int l0 = blockIdx.x * 64;
    const int t = threadIdx.x;
    const int lane = t & 63;
    const int bid = blockIdx.y * gridDim.x + blockIdx.x;
    const int hbase = __builtin_amdgcn_readfirstlane(t >> 6) * 32;
    const float* wbase = whT + hbase;

    float acc[32];
#pragma unroll
    for (int j = 0; j < 32; ++j) acc[j] = 0.f;

    const float* zb = z + (size_t)b * DD * LL;
    const int skk = t >> 4, sl4 = (t & 15) * 4;

    for (int kk0 = 0; kk0 < DD; kk0 += 32) {
        __syncthreads();
        {
            float4 gv = *(const float4*)(zb + (size_t)(kk0 + skk) * LL + l0 + sl4);
            z_lds[(sl4 + 0) * 33 + skk] = gv.x;
            z_lds[(sl4 + 1) * 33 + skk] = gv.y;
            z_lds[(sl4 + 2) * 33 + skk] = gv.z;
            z_lds[(sl4 + 3) * 33 + skk] = gv.w;
        }
        __syncthreads();
#pragma unroll
        for (int kt = 0; kt < 8; ++kt) {
            float4 zq = *(const float4*)&z_lds[lane * 33 + kt * 4];
#pragma unroll
            for (int k4 = 0; k4 < 4; ++k4) {
                float zv = (&zq.x)[k4];
                const float* wp = wbase + (size_t)(kk0 + kt * 4 + k4) * HH;
#pragma unroll
                for (int j = 0; j < 32; ++j)
                    acc[j] = fmaf(zv, wp[j], acc[j]);
            }
        }
    }

    const float SQ512 = sqrtf(512.0f);
    float* hb = hn + (size_t)bid * (64 * HH) + (size_t)lane * HH + hbase;
#pragma unroll
    for (int q = 0; q < 8; ++q) {
        float4 v;
        v.x = acc[q * 4 + 0] / SQ512;
        v.y = acc[q * 4 + 1] / SQ512;
        v.z = acc[q * 4 + 2] / SQ512;
        v.w = acc[q * 4 + 3] / SQ512;
        *(float4*)(hb + q * 4) = v;
    }
}

// ---------------------------------------------------------------- kernel B: rms + screen + verify + loss
// Screen restored to the MEASURED-172us structure (round-14 submission): 2-pass mg loop,
// ah[2][8] resident, each bh load feeds TWO MFMAs. Decision math bit-identical.
__global__ __launch_bounds__(512, 4) void select_kernel(const float* __restrict__ hn,
                                                        const float* __restrict__ cbn,
                                                        const u16* __restrict__ cb_hi,
                                                        int* __restrict__ inds_i,
                                                        float* __restrict__ partials) {
    __shared__ float hsm[64 * HST];     // 66,560 B
    __shared__ float cand_v[64][8][2];  // 4,096 (aliased: rtmp, scl, exv)
    __shared__ int   cand_i[64][8][2];  // 4,096
    __shared__ int   c4i[64][4];        // 1,024
    __shared__ int   ind_sm[64];        // 256
    __shared__ float sbuf[8];           // 32

    float* rtmp = &cand_v[0][0][0];
    float* scl  = &cand_v[0][0][0] + 128;
    float (*exv)[4] = (float(*)[4])&cand_v[0][0][0];

    const int b = blockIdx.y;
    const int l0 = blockIdx.x * 64;
    const int t = threadIdx.x;
    const int bid = blockIdx.y * gridDim.x + blockIdx.x;

    // ---------------- load hn block -> hsm (f32 bit-preserving)
    {
        int row = t >> 3, c0 = (t & 7) * 32;
        const float* src = hn + (size_t)bid * (64 * HH) + row * HH + c0;
        float* dst = &hsm[row * HST + c0];
#pragma unroll
        for (int q = 0; q < 8; ++q)
            *(float4*)(dst + q * 4) = *(const float4*)(src + q * 4);
    }
    __syncthreads();

    // ---------------- rms (npy pairwise, bit-exact) + scale in place
    if (t < 128) {
        int row = t >> 1, half = t & 1;
        rtmp[t] = npy_pw128_sq(&hsm[row * HST + half * 128]);
    }
    __syncthreads();
    if (t < 64) {
        float ss = rtmp[t * 2] + rtmp[t * 2 + 1];
        float m = ss / 256.0f;
        scl[t] = 1.0f / sqrtf(m + FEPS);
    }
    __syncthreads();
    {
        int row = t >> 3, c0 = (t & 7) * 32;
        float s = scl[row];
        float* hp = &hsm[row * HST + c0];
#pragma unroll
        for (int k = 0; k < 32; ++k) hp[k] = hp[k] * s;
    }
    __syncthreads();   // scl/rtmp dead; cand region free

    // ---------------- MFMA hi-only screen: 2 passes x 2 M-tiles, shared bh per two MFMAs
    {
        const int lane = t & 63;
        const int wid = t >> 6;          // 8 waves, 256 codes each
        const int col = lane & 15;
        const int kg = lane >> 4;        // k = s*32 + kg*8 + e
#pragma unroll 1
        for (int mg = 0; mg < 2; ++mg) {
            s8v ah[2][8];
#pragma unroll
            for (int mt = 0; mt < 2; ++mt) {
                int arow = (mg * 2 + mt) * 16 + col;
#pragma unroll
                for (int s = 0; s < 8; ++s) {
                    const float* hp = &hsm[arow * HST + s * 32 + kg * 8];
                    float4 p = *(const float4*)hp;
                    float4 q = *(const float4*)(hp + 4);
                    s8v v;
                    v[0] = (short)bf16bits(p.x); v[1] = (short)bf16bits(p.y);
                    v[2] = (short)bf16bits(p.z); v[3] = (short)bf16bits(p.w);
                    v[4] = (short)bf16bits(q.x); v[5] = (short)bf16bits(q.y);
                    v[6] = (short)bf16bits(q.z); v[7] = (short)bf16bits(q.w);
                    ah[mt][s] = v;
                }
            }
            float v0[2][4], v1[2][4]; int i0[2][4], i1[2][4];
#pragma unroll
            for (int mt = 0; mt < 2; ++mt)
#pragma unroll
                for (int j = 0; j < 4; ++j) {
                    v0[mt][j] = -3.4e38f; v1[mt][j] = -3.4e38f;
                    i0[mt][j] = 0; i1[mt][j] = 0;
                }
#pragma unroll 1
            for (int it = 0; it < 16; ++it) {
                const int n0 = (wid * 16 + it) * 16;
                const u16* cbh = cb_hi + (size_t)(n0 + col) * HH;
                f32x4 a0 = {0.f, 0.f, 0.f, 0.f}, a1 = a0;
#pragma unroll
                for (int s = 0; s < 8; ++s) {
                    s8v bh = *(const s8v*)(cbh + s * 32 + kg * 8);
                    a0 = __builtin_amdgcn_mfma_f32_16x16x32_bf16(ah[0][s], bh, a0, 0, 0, 0);
                    a1 = __builtin_amdgcn_mfma_f32_16x16x32_bf16(ah[1][s], bh, a1, 0, 0, 0);
                }
                const int n = n0 + col;
#pragma unroll
                for (int j = 0; j < 4; ++j) {
                    {
                        float v = a0[j];
                        bool g0 = v > v0[0][j], g1 = v > v1[0][j];
                        v1[0][j] = g0 ? v0[0][j] : (g1 ? v : v1[0][j]);
                        i1[0][j] = g0 ? i0[0][j] : (g1 ? n : i1[0][j]);
                        v0[0][j] = g0 ? v : v0[0][j];
                        i0[0][j] = g0 ? n : i0[0][j];
                    }
                    {
                        float v = a1[j];
                        bool g0 = v > v0[1][j], g1 = v > v1[1][j];
                        v1[1][j] = g0 ? v0[1][j] : (g1 ? v : v1[1][j]);
                        i1[1][j] = g0 ? i0[1][j] : (g1 ? n : i1[1][j]);
                        v0[1][j] = g0 ? v : v0[1][j];
                        i0[1][j] = g0 ? n : i0[1][j];
                    }
                }
            }
#pragma unroll
            for (int m = 1; m < 16; m <<= 1) {
#pragma unroll
                for (int mt = 0; mt < 2; ++mt)
#pragma unroll
                    for (int j = 0; j < 4; ++j) {
                        float ov0 = __shfl_xor(v0[mt][j], m, 16);
                        int   oi0 = __shfl_xor(i0[mt][j], m, 16);
                        float ov1 = __shfl_xor(v1[mt][j], m, 16);
                        int   oi1 = __shfl_xor(i1[mt][j], m, 16);
                        bool a = ov0 > v0[mt][j];
                        float w0 = a ? ov0 : v0[mt][j]; int w0i = a ? oi0 : i0[mt][j];
                        float s0 = a ? v0[mt][j] : ov0; int s0i = a ? i0[mt][j] : oi0;
                        bool bgt = ov1 > v1[mt][j];
                        float w1 = bgt ? ov1 : v1[mt][j]; int w1i = bgt ? oi1 : i1[mt][j];
                        bool c2 = w1 > s0;
                        v0[mt][j] = w0; i0[mt][j] = w0i;
                        v1[mt][j] = c2 ? w1 : s0; i1[mt][j] = c2 ? w1i : s0i;
                    }
            }
            if (col == 0) {
#pragma unroll
                for (int mt = 0; mt < 2; ++mt)
#pragma unroll
                    for (int j = 0; j < 4; ++j) {
                        int row = (mg * 2 + mt) * 16 + kg * 4 + j;
                        cand_v[row][wid][0] = v0[mt][j]; cand_i[row][wid][0] = i0[mt][j];
                        cand_v[row][wid][1] = v1[mt][j]; cand_i[row][wid][1] = i1[mt][j];
                    }
            }
        }
    }
    __syncthreads();

    // ---------------- per-row top-4 of 16, sorted by n ascending
    if (t < 64) {
        float vv[16]; int ii[16];
#pragma unroll
        for (int w = 0; w < 8; ++w) {
            vv[w * 2] = cand_v[t][w][0];     ii[w * 2] = cand_i[t][w][0];
            vv[w * 2 + 1] = cand_v[t][w][1]; ii[w * 2 + 1] = cand_i[t][w][1];
        }
        int sel[4];
#pragma unroll
        for (int c = 0; c < 4; ++c) {
            float bv = -3.4e38f; int bj = 0;
#pragma unroll
            for (int q = 0; q < 16; ++q)
                if (vv[q] > bv) { bv = vv[q]; bj = q; }
            sel[c] = ii[bj];
            vv[bj] = -3.4e38f;
        }
#pragma unroll
        for (int a = 0; a < 3; ++a)
#pragma unroll
            for (int bq = 0; bq < 3 - a; ++bq)
                if (sel[bq] > sel[bq + 1]) { int tmp = sel[bq]; sel[bq] = sel[bq + 1]; sel[bq + 1] = tmp; }
#pragma unroll
        for (int c = 0; c < 4; ++c) c4i[t][c] = sel[c];
    }
    __syncthreads();   // cand_v dead; exv alias live

    // ---------------- exact f32 seq-FMA verify (bit-identical chain)
    if (t < 256) {
        int row = t >> 2, c = t & 3;
        int n = c4i[row][c];
        const float* hr = &hsm[row * HST];
        const float* cr = cbn + (size_t)n * HH;
        float a0 = 0.f;
#pragma unroll 4
        for (int k = 0; k < HH; k += 4) {
            float4 cv = *(const float4*)(cr + k);
            float4 hv = *(const float4*)&hr[k];
            a0 = fmaf(hv.x, cv.x, a0); a0 = fmaf(hv.y, cv.y, a0);
            a0 = fmaf(hv.z, cv.z, a0); a0 = fmaf(hv.w, cv.w, a0);
        }
        exv[row][c] = a0;
    }
    __syncthreads();
    if (t < 64) {
        float bv = -3.4e38f; int bi = 0;
#pragma unroll
        for (int c = 0; c < 4; ++c) {
            float v = exv[t][c];
            int n = c4i[t][c];
            if (v > bv) { bv = v; bi = n; }   // candidates n-ascending; strict > = first max
        }
        ind_sm[t] = bi;
        inds_i[b * LL + l0 + t] = bi;
    }
    __syncthreads();

    // ---------------- loss partial (validated)
    {
        int rr = t >> 3, kg2 = t & 7;
        const float* cq2 = cbn + (size_t)ind_sm[rr] * HH;
        const float* hr = &hsm[rr * HST];
        float s = 0.f;
#pragma unroll
        for (int k = kg2 * 32; k < kg2 * 32 + 32; k += 4) {
            float4 cv = *(const float4*)(cq2 + k);
            float4 hv = *(const float4*)(hr + k);
            float e0 = cv.x - hv.x, e1 = cv.y - hv.y;
            float e2 = cv.z - hv.z, e3 = cv.w - hv.w;
            s = fmaf(e0, e0, s); s = fmaf(e1, e1, s);
            s = fmaf(e2, e2, s); s = fmaf(e3, e3, s);
        }
        s = breduce512_f32(s, sbuf);
        if (t == 0) partials[bid] = s;
    }
}

// ---------------------------------------------------------------- loss final (512 partials)
__global__ __launch_bounds__(256) void loss_final_kernel(const float* __restrict__ partials,
                                                         float* __restrict__ out_f32) {
    __shared__ double dbuf[8];
    const int t = threadIdx.x;
    double v = (double)partials[t] + (double)partials[t + 256];
    double s = breduce256_f64(v, dbuf);
    if (t == 0) {
        double mean = s / (double)((size_t)BB * LL * HH);
        out_f32[LOSS_OFF] = (float)(mean * 1.25);
    }
}

// ---------------------------------------------------------------- inds epilogue
__global__ __launch_bounds__(256) void epilogue_kernel(const int* __restrict__ inds_i,
                                                       float* __restrict__ out_f32) {
    int idx = blockIdx.x * 256 + threadIdx.x;
    if (idx < BB * LL) out_f32[IND_OFF + idx] = (float)inds_i[idx];
}

// ---------------------------------------------------------------- gemm_out: bf16 MFMA (validated rounds 17/18)
__global__ __launch_bounds__(256, 4) void gemm_out_kernel(const u16* __restrict__ cb_hi,
                                                          const int* __restrict__ inds_i,
                                                          const u16* __restrict__ wo_bf,
                                                          float* __restrict__ out_f32) {
    __shared__ alignas(16) u16 zq[64 * 264];   // gathered z_q rows, bf16
    __shared__ int inds_s[64];
    const int b = blockIdx.z;
    const int d0 = blockIdx.y * 64;
    const int l0 = blockIdx.x * 64;
    const int t = threadIdx.x;
    if (t < 64) {
        int ii = inds_i[b * LL + l0 + t];
        inds_s[t] = min(max(ii, 0), NN - 1);
    }
    __syncthreads();
    {   // stage: thread copies its 64-u16 quarter with eight 16B stores
        int li = t >> 2, qt = t & 3;
        const u16* src = cb_hi + (size_t)inds_s[li] * HH + qt * 64;
        u16* dst = &zq[li * 264 + qt * 64];
#pragma unroll
        for (int q = 0; q < 8; ++q)
            *(s8v*)(dst + q * 8) = *(const s8v*)(src + q * 8);
    }
    __syncthreads();

    const int lane = t & 63;
    const int wid = t >> 6;          // 4 waves -> d slice d0 + wid*16
    const int col = lane & 15;
    const int kg = lane >> 4;
    s8v aw[8];
    {
        const u16* wp = wo_bf + (size_t)(d0 + wid * 16 + col) * HH;
#pragma unroll
        for (int s = 0; s < 8; ++s)
            aw[s] = *(const s8v*)(wp + s * 32 + kg * 8);
    }
#pragma unroll
    for (int lt = 0; lt < 4; ++lt) {
        f32x4 c = {0.f, 0.f, 0.f, 0.f};
#pragma unroll
        for (int s = 0; s < 8; ++s) {
            s8v bz = *(const s8v*)&zq[(lt * 16 + col) * 264 + s * 32 + kg * 8];
            c = __builtin_amdgcn_mfma_f32_16x16x32_bf16(aw[s], bz, c, 0, 0, 0);
        }
        int l = l0 + lt * 16 + col;
#pragma unroll
        for (int j = 0; j < 4; ++j) {
            int d = d0 + wid * 16 + kg * 4 + j;
            out_f32[((size_t)b * DD + d) * LL + l] = c[j] * 0.0625f;   // /sqrt(256) == /16 exact
        }
    }
}

extern "C" void kernel_launch(void* const* d_in, const int* in_sizes, int n_in,
                              void* d_out, int out_size, void* d_ws, size_t ws_size,
                              hipStream_t stream) {
    const float* z        = (const float*)d_in[0];
    const float* w_in     = (const float*)d_in[1];
    const float* codebook = (const float*)d_in[2];
    const float* w_out    = (const float*)d_in[3];

    char* ws = (char*)d_ws;
    size_t off = 0;
    float* whT = (float*)(ws + off); off += (size_t)DD * HH * 4;        // 512 KB
    float* cbn = (float*)(ws + off); off += (size_t)NN * HH * 4;        // 2 MB
    int* inds_i = (int*)(ws + off);  off += (size_t)BB * LL * 4;        // 128 KB
    float* partials = (float*)(ws + off); off += 512 * 4;               // 2 KB
    u16* cb_hi = (u16*)(ws + off); off += (size_t)NN * HH * 2;          // 1 MB
    u16* wo_bf = (u16*)(ws + off); off += (size_t)DD * HH * 2;          // 256 KB
    float* hn = (float*)(ws + off); off += (size_t)BB * LL * HH * 4;    // 32 MB

    float* out_f32 = (float*)d_out;

    prep_kernel<<<HH + DD + NN, 256, 0, stream>>>(w_in, codebook, w_out, whT, cbn, wo_bf, cb_hi);
    gemm_h_kernel<<<dim3(LL / 64, BB), 512, 0, stream>>>(z, whT, hn);
    select_kernel<<<dim3(LL / 64, BB), 512, 0, stream>>>(hn, cbn, cb_hi, inds_i, partials);
    loss_final_kernel<<<1, 256, 0, stream>>>(partials, out_f32);
    epilogue_kernel<<<(BB * LL + 255) / 256, 256, 0, stream>>>(inds_i, out_f32);
    gemm_out_kernel<<<dim3(LL / 64, DD / 64, BB), 256, 0, stream>>>(cb_hi, inds_i, wo_bf, out_f32);
}